// Round 2
// baseline (451.246 us; speedup 1.0000x reference)
//
#include <hip/hip_runtime.h>
#include <hip/hip_bf16.h>

typedef unsigned short u16;
typedef unsigned int u32;
typedef __bf16 bf16x8 __attribute__((ext_vector_type(8)));
typedef float f32x4 __attribute__((ext_vector_type(4)));
typedef unsigned int u32x4 __attribute__((ext_vector_type(4)));

// ---------------- constants ----------------
#define BATCH 8
#define SEQ   2048
#define DIM   1024
#define M_TOT (BATCH * SEQ)      // 16384
#define N_QKV (3 * DIM)          // 3072

// workspace layout (bytes) — peak 201,326,592 (192 MiB)
//   [0, 100663296)            qkv bf16 (16384 x 3072)
//   [100663296, 134217728)    vt  bf16 (8 x 1024 x 2048)
//   [134217728, ...)          region C, time-multiplexed:
//       phase 1: xb bf16 (33,554,432) + wt bf16 (6,291,456)   [dead after QKV GEMM]
//       phase 2: S/P bf16 (8 x 2048 x 2048 x 2 = 67,108,864)  [softmax in-place]
#define OFF_QKV  ((size_t)0)
#define OFF_VT   ((size_t)100663296)
#define OFF_C    ((size_t)134217728)
#define OFF_XB   OFF_C
#define OFF_WT   (OFF_C + (size_t)33554432)
#define OFF_S    OFF_C

__device__ __forceinline__ u16 f32_to_bf16(float f) {
    u32 u = __builtin_bit_cast(u32, f);
    u = (u + 0x7fffu + ((u >> 16) & 1u)) >> 16;
    return (u16)u;
}

__device__ __forceinline__ float bf16_to_f32(u16 h) {
    u32 u = ((u32)h) << 16;
    return __builtin_bit_cast(float, u);
}

__device__ __forceinline__ bf16x8 lds_load8(const u16* p) {
    return __builtin_bit_cast(bf16x8, *(const u32x4*)p);
}

// Stage a 128x32 bf16 tile (row-major, leading dim = lda elements) into LDS
// via global_load_lds width=16. 256 threads, 2 chunks of 16B each.
__device__ __forceinline__ void stage_tile(const u16* gA, size_t lda, u16* ldsA, int tid) {
    int wv = tid >> 6;
#pragma unroll
    for (int iss = 0; iss < 2; ++iss) {
        int c = iss * 256 + tid;          // chunk index 0..511
        int row = c >> 2;                 // 4 chunks (of 8 bf16) per 32-wide row
        int kcol = (c & 3) << 3;
        const u16* gp = gA + (size_t)row * lda + kcol;
        u16* lp = ldsA + (size_t)(iss * 256 + wv * 64) * 8;  // wave-uniform base
        __builtin_amdgcn_global_load_lds((const __attribute__((address_space(1))) void*)gp,
                                         (__attribute__((address_space(3))) void*)lp,
                                         16, 0, 0);
    }
}

// One BK=32 step: 4x4 fragments of 16x16x32, per-wave 64x64 of a 128x128 C tile.
__device__ __forceinline__ void mfma_step(const u16* ldsA, const u16* ldsB, int tid,
                                          f32x4 acc[4][4]) {
    int lane = tid & 63;
    int wv = tid >> 6;
    int wr = (wv >> 1) * 64, wc = (wv & 1) * 64;
    int lrow = lane & 15, koff = (lane >> 4) * 8;
    bf16x8 a[4], b[4];
#pragma unroll
    for (int i = 0; i < 4; ++i) {
        a[i] = lds_load8(&ldsA[(wr + i * 16 + lrow) * 32 + koff]);
        b[i] = lds_load8(&ldsB[(wc + i * 16 + lrow) * 32 + koff]);
    }
#pragma unroll
    for (int i = 0; i < 4; ++i)
#pragma unroll
        for (int j = 0; j < 4; ++j)
            acc[i][j] = __builtin_amdgcn_mfma_f32_16x16x32_bf16(a[i], b[j], acc[i][j], 0, 0, 0);
}

// ---------------- kernel 1: cast x fp32 -> bf16 ----------------
__global__ __launch_bounds__(256) void cast_x_kernel(const float* __restrict__ x,
                                                     u16* __restrict__ xb) {
    size_t g = (size_t)blockIdx.x * 256 + threadIdx.x;   // group of 4 elems
    f32x4 v = ((const f32x4*)x)[g];
    u16 o[4] = {f32_to_bf16(v.x), f32_to_bf16(v.y), f32_to_bf16(v.z), f32_to_bf16(v.w)};
    *(unsigned long long*)(xb + g * 4) = *(const unsigned long long*)o;
}

// ---------------- kernel 2: transpose-cast W [k][n] fp32 -> Wt [n][k] bf16 ----------------
__global__ __launch_bounds__(256) void transpose_w_kernel(const float* __restrict__ wq,
                                                          const float* __restrict__ wk,
                                                          const float* __restrict__ wv,
                                                          u16* __restrict__ wt) {
    __shared__ __align__(16) u16 tile[64][80];
    const float* w = blockIdx.z == 0 ? wq : (blockIdx.z == 1 ? wk : wv);
    int k0 = blockIdx.x * 64, n0 = blockIdx.y * 64;
    for (int g = threadIdx.x; g < 1024; g += 256) {
        int r = g >> 4, c = (g & 15) << 2;
        f32x4 v = *(const f32x4*)(w + (size_t)(k0 + r) * 1024 + n0 + c);
        tile[r][c + 0] = f32_to_bf16(v.x);
        tile[r][c + 1] = f32_to_bf16(v.y);
        tile[r][c + 2] = f32_to_bf16(v.z);
        tile[r][c + 3] = f32_to_bf16(v.w);
    }
    __syncthreads();
    u16* out = wt + (size_t)blockIdx.z * 1024 * 1024;
    for (int g = threadIdx.x; g < 512; g += 256) {
        int nr = g >> 3, kc = (g & 7) << 3;
        __align__(16) u16 tmp[8];
#pragma unroll
        for (int i = 0; i < 8; ++i) tmp[i] = tile[kc + i][nr];
        *(u32x4*)(out + (size_t)(n0 + nr) * 1024 + k0 + kc) = *(const u32x4*)tmp;
    }
}

// ---------------- kernel 3: QKV GEMM: qkv[m][n'] = xb[m][:] . wt[n'][:] ----------------
__global__ __launch_bounds__(256, 2) void gemm_qkv_kernel(const u16* __restrict__ xb,
                                                          const u16* __restrict__ wt,
                                                          u16* __restrict__ qkv) {
    __shared__ __align__(16) u16 ldsA[128 * 32];
    __shared__ __align__(16) u16 ldsB[128 * 32];
    int nt = blockIdx.x, mt = blockIdx.y;
    const u16* A = xb + (size_t)mt * 128 * 1024;
    const u16* B = wt + (size_t)nt * 128 * 1024;
    int tid = threadIdx.x;
    f32x4 acc[4][4] = {};
    for (int kt = 0; kt < 32; ++kt) {
        __syncthreads();
        stage_tile(A + kt * 32, 1024, ldsA, tid);
        stage_tile(B + kt * 32, 1024, ldsB, tid);
        __syncthreads();
        mfma_step(ldsA, ldsB, tid, acc);
    }
    int lane = tid & 63, wv = tid >> 6;
    int wr = (wv >> 1) * 64, wc = (wv & 1) * 64;
    int r0 = (lane >> 4) * 4, c0 = lane & 15;
    size_t mbase = (size_t)mt * 128;
    int nbase = nt * 128;
#pragma unroll
    for (int i = 0; i < 4; ++i)
#pragma unroll
        for (int j = 0; j < 4; ++j) {
            int col = nbase + wc + j * 16 + c0;
            float scale = (col < 1024) ? 0.03125f : 1.0f;  // fold 1/sqrt(1024) into Q
#pragma unroll
            for (int r = 0; r < 4; ++r) {
                int row = wr + i * 16 + r0 + r;
                qkv[(mbase + row) * (size_t)N_QKV + col] = f32_to_bf16(acc[i][j][r] * scale);
            }
        }
}

// ---------------- kernel 4: transpose V -> Vt [b][d][m] ----------------
__global__ __launch_bounds__(256) void transpose_v_kernel(const u16* __restrict__ qkv,
                                                          u16* __restrict__ vt) {
    __shared__ __align__(16) u16 tile[64][80];
    int m0 = blockIdx.x * 64, d0 = blockIdx.y * 64, b = blockIdx.z;
    const u16* src = qkv + (size_t)b * SEQ * N_QKV + 2048;  // V columns
    for (int g = threadIdx.x; g < 512; g += 256) {
        int r = g >> 3, c = (g & 7) << 3;
        *(u32x4*)&tile[r][c] = *(const u32x4*)(src + (size_t)(m0 + r) * N_QKV + d0 + c);
    }
    __syncthreads();
    u16* dst = vt + (size_t)b * DIM * SEQ;
    for (int g = threadIdx.x; g < 512; g += 256) {
        int dr = g >> 3, mc = (g & 7) << 3;
        __align__(16) u16 tmp[8];
#pragma unroll
        for (int i = 0; i < 8; ++i) tmp[i] = tile[mc + i][dr];
        *(u32x4*)(dst + (size_t)(d0 + dr) * SEQ + m0 + mc) = *(const u32x4*)tmp;
    }
}

// ---------------- kernel 5: S = Q . K^T (causal tile skip), bf16 output ----------------
__global__ __launch_bounds__(256, 2) void gemm_scores_kernel(const u16* __restrict__ qkv,
                                                             u16* __restrict__ S) {
    int mtile = blockIdx.x, ntile = blockIdx.y, b = blockIdx.z;
    if (mtile > ntile) return;  // tile fully above the diagonal: never read
    __shared__ __align__(16) u16 ldsA[128 * 32];
    __shared__ __align__(16) u16 ldsB[128 * 32];
    const u16* A = qkv + (size_t)b * SEQ * N_QKV + (size_t)ntile * 128 * N_QKV;        // Q rows
    const u16* B = qkv + (size_t)b * SEQ * N_QKV + (size_t)mtile * 128 * N_QKV + 1024; // K rows
    int tid = threadIdx.x;
    f32x4 acc[4][4] = {};
    for (int kt = 0; kt < 32; ++kt) {
        __syncthreads();
        stage_tile(A + kt * 32, N_QKV, ldsA, tid);
        stage_tile(B + kt * 32, N_QKV, ldsB, tid);
        __syncthreads();
        mfma_step(ldsA, ldsB, tid, acc);
    }
    u16* out = S + (size_t)b * SEQ * SEQ + (size_t)ntile * 128 * SEQ + (size_t)mtile * 128;
    int lane = tid & 63, wv = tid >> 6;
    int wr = (wv >> 1) * 64, wc = (wv & 1) * 64;
    int r0 = (lane >> 4) * 4, c0 = lane & 15;
#pragma unroll
    for (int i = 0; i < 4; ++i)
#pragma unroll
        for (int j = 0; j < 4; ++j) {
            int col = wc + j * 16 + c0;
#pragma unroll
            for (int r = 0; r < 4; ++r) {
                int row = wr + i * 16 + r0 + r;
                out[(size_t)row * SEQ + col] = f32_to_bf16(acc[i][j][r]);
            }
        }
}

// ---------------- kernel 6: row softmax over bf16 S, in-place write P bf16 ----------------
// Each thread reads only indices {t, t+256, ...} and writes the same indices,
// so the in-place overwrite has no cross-thread hazard.
__global__ __launch_bounds__(256) void softmax_kernel(u16* __restrict__ SP) {
    int gr = blockIdx.x;
    int b = gr >> 11, n = gr & 2047;
    u16* s = SP + ((size_t)b * SEQ + n) * SEQ;
    __shared__ float buf[2048];
    __shared__ float red[4];
    int t = threadIdx.x;
    int len = n + 1;
    float lmax = -3.0e38f;
    for (int m = t; m < len; m += 256) {
        float v = bf16_to_f32(s[m]);
        buf[m] = v;
        lmax = fmaxf(lmax, v);
    }
#pragma unroll
    for (int off = 32; off; off >>= 1) lmax = fmaxf(lmax, __shfl_xor(lmax, off, 64));
    if ((t & 63) == 0) red[t >> 6] = lmax;
    __syncthreads();
    float gmax = fmaxf(fmaxf(red[0], red[1]), fmaxf(red[2], red[3]));
    float lsum = 0.f;
    for (int m = t; m < len; m += 256) {
        float e = __expf(buf[m] - gmax);
        buf[m] = e;
        lsum += e;
    }
#pragma unroll
    for (int off = 32; off; off >>= 1) lsum += __shfl_xor(lsum, off, 64);
    __syncthreads();
    if ((t & 63) == 0) red[t >> 6] = lsum;
    __syncthreads();
    float inv = 1.0f / (red[0] + red[1] + red[2] + red[3]);
    for (int m = t; m < 2048; m += 256) {
        float v = (m < len) ? buf[m] * inv : 0.0f;
        s[m] = f32_to_bf16(v);
    }
}

// ---------------- kernel 7: O = P . V (via Vt), causal K truncation ----------------
__global__ __launch_bounds__(256, 2) void gemm_out_kernel(const u16* __restrict__ P,
                                                          const u16* __restrict__ vt,
                                                          float* __restrict__ O) {
    __shared__ __align__(16) u16 ldsA[128 * 32];
    __shared__ __align__(16) u16 ldsB[128 * 32];
    int dt = blockIdx.x, ntile = blockIdx.y, b = blockIdx.z;
    const u16* A = P + (size_t)b * SEQ * SEQ + (size_t)ntile * 128 * SEQ;
    const u16* B = vt + (size_t)b * DIM * SEQ + (size_t)dt * 128 * SEQ;
    int tid = threadIdx.x;
    f32x4 acc[4][4] = {};
    int kTiles = ntile * 4 + 4;  // keys beyond n0+127 have P == 0
    for (int kt = 0; kt < kTiles; ++kt) {
        __syncthreads();
        stage_tile(A + kt * 32, SEQ, ldsA, tid);
        stage_tile(B + kt * 32, SEQ, ldsB, tid);
        __syncthreads();
        mfma_step(ldsA, ldsB, tid, acc);
    }
    float* out = O + (size_t)b * SEQ * DIM + (size_t)ntile * 128 * DIM + (size_t)dt * 128;
    int lane = tid & 63, wv = tid >> 6;
    int wr = (wv >> 1) * 64, wc = (wv & 1) * 64;
    int r0 = (lane >> 4) * 4, c0 = lane & 15;
#pragma unroll
    for (int i = 0; i < 4; ++i)
#pragma unroll
        for (int j = 0; j < 4; ++j) {
            int col = wc + j * 16 + c0;
#pragma unroll
            for (int r = 0; r < 4; ++r) {
                int row = wr + i * 16 + r0 + r;
                out[(size_t)row * DIM + col] = acc[i][j][r];
            }
        }
}

extern "C" void kernel_launch(void* const* d_in, const int* in_sizes, int n_in,
                              void* d_out, int out_size, void* d_ws, size_t ws_size,
                              hipStream_t stream) {
    const float* x = (const float*)d_in[0];
    const float* wq = (const float*)d_in[1];
    const float* wk = (const float*)d_in[2];
    const float* wv = (const float*)d_in[3];
    char* ws = (char*)d_ws;
    u16* qkv = (u16*)(ws + OFF_QKV);
    u16* vt = (u16*)(ws + OFF_VT);
    u16* xb = (u16*)(ws + OFF_XB);
    u16* wt = (u16*)(ws + OFF_WT);
    u16* S = (u16*)(ws + OFF_S);   // aliases xb/wt region (dead by then)
    float* O = (float*)d_out;

    cast_x_kernel<<<M_TOT * DIM / 4 / 256, 256, 0, stream>>>(x, xb);
    transpose_w_kernel<<<dim3(16, 16, 3), 256, 0, stream>>>(wq, wk, wv, wt);
    gemm_qkv_kernel<<<dim3(N_QKV / 128, M_TOT / 128), 256, 0, stream>>>(xb, wt, qkv);
    transpose_v_kernel<<<dim3(SEQ / 64, DIM / 64, BATCH), 256, 0, stream>>>(qkv, vt);
    gemm_scores_kernel<<<dim3(SEQ / 128, SEQ / 128, BATCH), 256, 0, stream>>>(qkv, S);
    softmax_kernel<<<BATCH * SEQ, 256, 0, stream>>>(S);
    gemm_out_kernel<<<dim3(DIM / 128, SEQ / 128, BATCH), 256, 0, stream>>>(S, vt, O);
}

// Round 3
// 448.865 us; speedup vs baseline: 1.0053x; 1.0053x over previous
//
#include <hip/hip_runtime.h>
#include <hip/hip_bf16.h>

typedef unsigned short u16;
typedef unsigned int u32;
typedef __bf16 bf16x8 __attribute__((ext_vector_type(8)));
typedef float f32x4 __attribute__((ext_vector_type(4)));
typedef unsigned int u32x4 __attribute__((ext_vector_type(4)));

// ---------------- constants ----------------
#define BATCH 8
#define SEQ   2048
#define DIM   1024
#define M_TOT (BATCH * SEQ)      // 16384
#define N_QKV (3 * DIM)          // 3072

// workspace layout (bytes) — peak 201,326,592 (192 MiB)
//   [0, 100663296)            qkv bf16 (16384 x 3072)
//   [100663296, 134217728)    vt  bf16 (8 x 1024 x 2048)
//   [134217728, ...)          region C, time-multiplexed:
//       phase 1: xb bf16 (33,554,432) + wt bf16 (6,291,456)   [dead after QKV GEMM]
//       phase 2: S/P bf16 (8 x 2048 x 2048 x 2 = 67,108,864)  [softmax in-place]
#define OFF_QKV  ((size_t)0)
#define OFF_VT   ((size_t)100663296)
#define OFF_C    ((size_t)134217728)
#define OFF_XB   OFF_C
#define OFF_WT   (OFF_C + (size_t)33554432)
#define OFF_S    OFF_C

__device__ __forceinline__ u16 f32_to_bf16(float f) {
    u32 u = __builtin_bit_cast(u32, f);
    u = (u + 0x7fffu + ((u >> 16) & 1u)) >> 16;
    return (u16)u;
}

__device__ __forceinline__ float bf16_to_f32(u16 h) {
    u32 u = ((u32)h) << 16;
    return __builtin_bit_cast(float, u);
}

__device__ __forceinline__ bf16x8 lds_load8(const u16* p) {
    return __builtin_bit_cast(bf16x8, *(const u32x4*)p);
}

// Stage a 128x32 bf16 tile into LDS via global_load_lds width=16.
// LDS layout is XOR-swizzled at 16B-chunk granularity:
//   chunk slot s holds (row = s>>2, kg = (s&3) ^ ((s>>3)&3))
// i.e. data (row,kg) lives at slot row*4 + (kg ^ ((row>>1)&3)).
// This spreads a row-cluster's 16 lanes across all 8 bank groups (2-way, free)
// instead of 2 groups (8-way conflict) — see R2 counters (1.26e7 conflicts).
__device__ __forceinline__ void stage_tile(const u16* gA, size_t lda, u16* ldsA, int tid) {
    int wv = tid >> 6;
#pragma unroll
    for (int iss = 0; iss < 2; ++iss) {
        int c = iss * 256 + tid;          // chunk slot 0..511
        int row = c >> 2;                 // 4 chunks (of 8 bf16) per 32-wide row
        int kg = (c & 3) ^ ((c >> 3) & 3);  // swizzled k-group for this slot
        const u16* gp = gA + (size_t)row * lda + (kg << 3);
        u16* lp = ldsA + (size_t)(iss * 256 + wv * 64) * 8;  // wave-uniform base
        __builtin_amdgcn_global_load_lds((const __attribute__((address_space(1))) void*)gp,
                                         (__attribute__((address_space(3))) void*)lp,
                                         16, 0, 0);
    }
}

// One BK=32 step: 4x4 fragments of 16x16x32, per-wave 64x64 of a 128x128 C tile.
// Reads use the swizzled koff; ((row>>1)&3) is invariant across the i-loop
// (rows step by 16), so the swizzle costs zero inner-loop VALU.
__device__ __forceinline__ void mfma_step(const u16* ldsA, const u16* ldsB, int tid,
                                          f32x4 acc[4][4]) {
    int lane = tid & 63;
    int wv = tid >> 6;
    int wr = (wv >> 1) * 64, wc = (wv & 1) * 64;
    int lrow = lane & 15, kg = lane >> 4;
    int skgA = ((kg ^ (((wr + lrow) >> 1) & 3)) << 3);
    int skgB = ((kg ^ (((wc + lrow) >> 1) & 3)) << 3);
    bf16x8 a[4], b[4];
#pragma unroll
    for (int i = 0; i < 4; ++i) {
        a[i] = lds_load8(&ldsA[(wr + i * 16 + lrow) * 32 + skgA]);
        b[i] = lds_load8(&ldsB[(wc + i * 16 + lrow) * 32 + skgB]);
    }
#pragma unroll
    for (int i = 0; i < 4; ++i)
#pragma unroll
        for (int j = 0; j < 4; ++j)
            acc[i][j] = __builtin_amdgcn_mfma_f32_16x16x32_bf16(a[i], b[j], acc[i][j], 0, 0, 0);
}

// ---------------- kernel 1: cast x fp32 -> bf16 ----------------
__global__ __launch_bounds__(256) void cast_x_kernel(const float* __restrict__ x,
                                                     u16* __restrict__ xb) {
    size_t g = (size_t)blockIdx.x * 256 + threadIdx.x;   // group of 4 elems
    f32x4 v = ((const f32x4*)x)[g];
    u16 o[4] = {f32_to_bf16(v.x), f32_to_bf16(v.y), f32_to_bf16(v.z), f32_to_bf16(v.w)};
    *(unsigned long long*)(xb + g * 4) = *(const unsigned long long*)o;
}

// ---------------- kernel 2: transpose-cast W [k][n] fp32 -> Wt [n][k] bf16 ----------------
__global__ __launch_bounds__(256) void transpose_w_kernel(const float* __restrict__ wq,
                                                          const float* __restrict__ wk,
                                                          const float* __restrict__ wv,
                                                          u16* __restrict__ wt) {
    __shared__ __align__(16) u16 tile[64][80];
    const float* w = blockIdx.z == 0 ? wq : (blockIdx.z == 1 ? wk : wv);
    int k0 = blockIdx.x * 64, n0 = blockIdx.y * 64;
    for (int g = threadIdx.x; g < 1024; g += 256) {
        int r = g >> 4, c = (g & 15) << 2;
        f32x4 v = *(const f32x4*)(w + (size_t)(k0 + r) * 1024 + n0 + c);
        tile[r][c + 0] = f32_to_bf16(v.x);
        tile[r][c + 1] = f32_to_bf16(v.y);
        tile[r][c + 2] = f32_to_bf16(v.z);
        tile[r][c + 3] = f32_to_bf16(v.w);
    }
    __syncthreads();
    u16* out = wt + (size_t)blockIdx.z * 1024 * 1024;
    for (int g = threadIdx.x; g < 512; g += 256) {
        int nr = g >> 3, kc = (g & 7) << 3;
        __align__(16) u16 tmp[8];
#pragma unroll
        for (int i = 0; i < 8; ++i) tmp[i] = tile[kc + i][nr];
        *(u32x4*)(out + (size_t)(n0 + nr) * 1024 + k0 + kc) = *(const u32x4*)tmp;
    }
}

// ---------------- kernel 3: QKV GEMM: qkv[m][n'] = xb[m][:] . wt[n'][:] ----------------
__global__ __launch_bounds__(256, 2) void gemm_qkv_kernel(const u16* __restrict__ xb,
                                                          const u16* __restrict__ wt,
                                                          u16* __restrict__ qkv) {
    __shared__ __align__(16) u16 ldsA[128 * 32];
    __shared__ __align__(16) u16 ldsB[128 * 32];
    int nt = blockIdx.x, mt = blockIdx.y;
    const u16* A = xb + (size_t)mt * 128 * 1024;
    const u16* B = wt + (size_t)nt * 128 * 1024;
    int tid = threadIdx.x;
    f32x4 acc[4][4] = {};
    for (int kt = 0; kt < 32; ++kt) {
        __syncthreads();
        stage_tile(A + kt * 32, 1024, ldsA, tid);
        stage_tile(B + kt * 32, 1024, ldsB, tid);
        __syncthreads();
        mfma_step(ldsA, ldsB, tid, acc);
    }
    int lane = tid & 63, wv = tid >> 6;
    int wr = (wv >> 1) * 64, wc = (wv & 1) * 64;
    int r0 = (lane >> 4) * 4, c0 = lane & 15;
    size_t mbase = (size_t)mt * 128;
    int nbase = nt * 128;
#pragma unroll
    for (int i = 0; i < 4; ++i)
#pragma unroll
        for (int j = 0; j < 4; ++j) {
            int col = nbase + wc + j * 16 + c0;
            float scale = (col < 1024) ? 0.03125f : 1.0f;  // fold 1/sqrt(1024) into Q
#pragma unroll
            for (int r = 0; r < 4; ++r) {
                int row = wr + i * 16 + r0 + r;
                qkv[(mbase + row) * (size_t)N_QKV + col] = f32_to_bf16(acc[i][j][r] * scale);
            }
        }
}

// ---------------- kernel 4: transpose V -> Vt [b][d][m] ----------------
__global__ __launch_bounds__(256) void transpose_v_kernel(const u16* __restrict__ qkv,
                                                          u16* __restrict__ vt) {
    __shared__ __align__(16) u16 tile[64][80];
    int m0 = blockIdx.x * 64, d0 = blockIdx.y * 64, b = blockIdx.z;
    const u16* src = qkv + (size_t)b * SEQ * N_QKV + 2048;  // V columns
    for (int g = threadIdx.x; g < 512; g += 256) {
        int r = g >> 3, c = (g & 7) << 3;
        *(u32x4*)&tile[r][c] = *(const u32x4*)(src + (size_t)(m0 + r) * N_QKV + d0 + c);
    }
    __syncthreads();
    u16* dst = vt + (size_t)b * DIM * SEQ;
    for (int g = threadIdx.x; g < 512; g += 256) {
        int dr = g >> 3, mc = (g & 7) << 3;
        __align__(16) u16 tmp[8];
#pragma unroll
        for (int i = 0; i < 8; ++i) tmp[i] = tile[mc + i][dr];
        *(u32x4*)(dst + (size_t)(d0 + dr) * SEQ + m0 + mc) = *(const u32x4*)tmp;
    }
}

// ---------------- kernel 5: S = Q . K^T (causal tile skip), bf16 output ----------------
__global__ __launch_bounds__(256, 2) void gemm_scores_kernel(const u16* __restrict__ qkv,
                                                             u16* __restrict__ S) {
    int mtile = blockIdx.x, ntile = blockIdx.y, b = blockIdx.z;
    if (mtile > ntile) return;  // tile fully above the diagonal: never read
    __shared__ __align__(16) u16 ldsA[128 * 32];
    __shared__ __align__(16) u16 ldsB[128 * 32];
    const u16* A = qkv + (size_t)b * SEQ * N_QKV + (size_t)ntile * 128 * N_QKV;        // Q rows
    const u16* B = qkv + (size_t)b * SEQ * N_QKV + (size_t)mtile * 128 * N_QKV + 1024; // K rows
    int tid = threadIdx.x;
    f32x4 acc[4][4] = {};
    for (int kt = 0; kt < 32; ++kt) {
        __syncthreads();
        stage_tile(A + kt * 32, N_QKV, ldsA, tid);
        stage_tile(B + kt * 32, N_QKV, ldsB, tid);
        __syncthreads();
        mfma_step(ldsA, ldsB, tid, acc);
    }
    u16* out = S + (size_t)b * SEQ * SEQ + (size_t)ntile * 128 * SEQ + (size_t)mtile * 128;
    int lane = tid & 63, wv = tid >> 6;
    int wr = (wv >> 1) * 64, wc = (wv & 1) * 64;
    int r0 = (lane >> 4) * 4, c0 = lane & 15;
#pragma unroll
    for (int i = 0; i < 4; ++i)
#pragma unroll
        for (int j = 0; j < 4; ++j) {
            int col = wc + j * 16 + c0;
#pragma unroll
            for (int r = 0; r < 4; ++r) {
                int row = wr + i * 16 + r0 + r;
                out[(size_t)row * SEQ + col] = f32_to_bf16(acc[i][j][r]);
            }
        }
}

// ---------------- kernel 6: row softmax over bf16 S, in-place write P bf16 ----------------
// Each thread reads only indices {t, t+256, ...} and writes the same indices,
// so the in-place overwrite has no cross-thread hazard.
__global__ __launch_bounds__(256) void softmax_kernel(u16* __restrict__ SP) {
    int gr = blockIdx.x;
    int b = gr >> 11, n = gr & 2047;
    u16* s = SP + ((size_t)b * SEQ + n) * SEQ;
    __shared__ float buf[2048];
    __shared__ float red[4];
    int t = threadIdx.x;
    int len = n + 1;
    float lmax = -3.0e38f;
    for (int m = t; m < len; m += 256) {
        float v = bf16_to_f32(s[m]);
        buf[m] = v;
        lmax = fmaxf(lmax, v);
    }
#pragma unroll
    for (int off = 32; off; off >>= 1) lmax = fmaxf(lmax, __shfl_xor(lmax, off, 64));
    if ((t & 63) == 0) red[t >> 6] = lmax;
    __syncthreads();
    float gmax = fmaxf(fmaxf(red[0], red[1]), fmaxf(red[2], red[3]));
    float lsum = 0.f;
    for (int m = t; m < len; m += 256) {
        float e = __expf(buf[m] - gmax);
        buf[m] = e;
        lsum += e;
    }
#pragma unroll
    for (int off = 32; off; off >>= 1) lsum += __shfl_xor(lsum, off, 64);
    __syncthreads();
    if ((t & 63) == 0) red[t >> 6] = lsum;
    __syncthreads();
    float inv = 1.0f / (red[0] + red[1] + red[2] + red[3]);
    for (int m = t; m < 2048; m += 256) {
        float v = (m < len) ? buf[m] * inv : 0.0f;
        s[m] = f32_to_bf16(v);
    }
}

// ---------------- kernel 7: O = P . V (via Vt), causal K truncation ----------------
// ntile reversed so the longest blocks (kTiles=64) dispatch first (tail balance).
__global__ __launch_bounds__(256, 2) void gemm_out_kernel(const u16* __restrict__ P,
                                                          const u16* __restrict__ vt,
                                                          float* __restrict__ O) {
    __shared__ __align__(16) u16 ldsA[128 * 32];
    __shared__ __align__(16) u16 ldsB[128 * 32];
    int dt = blockIdx.x, b = blockIdx.z;
    int ntile = (SEQ / 128 - 1) - blockIdx.y;
    const u16* A = P + (size_t)b * SEQ * SEQ + (size_t)ntile * 128 * SEQ;
    const u16* B = vt + (size_t)b * DIM * SEQ + (size_t)dt * 128 * SEQ;
    int tid = threadIdx.x;
    f32x4 acc[4][4] = {};
    int kTiles = ntile * 4 + 4;  // keys beyond n0+127 have P == 0
    for (int kt = 0; kt < kTiles; ++kt) {
        __syncthreads();
        stage_tile(A + kt * 32, SEQ, ldsA, tid);
        stage_tile(B + kt * 32, SEQ, ldsB, tid);
        __syncthreads();
        mfma_step(ldsA, ldsB, tid, acc);
    }
    float* out = O + (size_t)b * SEQ * DIM + (size_t)ntile * 128 * DIM + (size_t)dt * 128;
    int lane = tid & 63, wv = tid >> 6;
    int wr = (wv >> 1) * 64, wc = (wv & 1) * 64;
    int r0 = (lane >> 4) * 4, c0 = lane & 15;
#pragma unroll
    for (int i = 0; i < 4; ++i)
#pragma unroll
        for (int j = 0; j < 4; ++j) {
            int col = wc + j * 16 + c0;
#pragma unroll
            for (int r = 0; r < 4; ++r) {
                int row = wr + i * 16 + r0 + r;
                out[(size_t)row * DIM + col] = acc[i][j][r];
            }
        }
}

extern "C" void kernel_launch(void* const* d_in, const int* in_sizes, int n_in,
                              void* d_out, int out_size, void* d_ws, size_t ws_size,
                              hipStream_t stream) {
    const float* x = (const float*)d_in[0];
    const float* wq = (const float*)d_in[1];
    const float* wk = (const float*)d_in[2];
    const float* wv = (const float*)d_in[3];
    char* ws = (char*)d_ws;
    u16* qkv = (u16*)(ws + OFF_QKV);
    u16* vt = (u16*)(ws + OFF_VT);
    u16* xb = (u16*)(ws + OFF_XB);
    u16* wt = (u16*)(ws + OFF_WT);
    u16* S = (u16*)(ws + OFF_S);   // aliases xb/wt region (dead by then)
    float* O = (float*)d_out;

    cast_x_kernel<<<M_TOT * DIM / 4 / 256, 256, 0, stream>>>(x, xb);
    transpose_w_kernel<<<dim3(16, 16, 3), 256, 0, stream>>>(wq, wk, wv, wt);
    gemm_qkv_kernel<<<dim3(N_QKV / 128, M_TOT / 128), 256, 0, stream>>>(xb, wt, qkv);
    transpose_v_kernel<<<dim3(SEQ / 64, DIM / 64, BATCH), 256, 0, stream>>>(qkv, vt);
    gemm_scores_kernel<<<dim3(SEQ / 128, SEQ / 128, BATCH), 256, 0, stream>>>(qkv, S);
    softmax_kernel<<<BATCH * SEQ, 256, 0, stream>>>(S);
    gemm_out_kernel<<<dim3(DIM / 128, SEQ / 128, BATCH), 256, 0, stream>>>(S, vt, O);
}

// Round 4
// 398.691 us; speedup vs baseline: 1.1318x; 1.1258x over previous
//
#include <hip/hip_runtime.h>
#include <hip/hip_bf16.h>

typedef unsigned short u16;
typedef unsigned int u32;
typedef __bf16 bf16x8 __attribute__((ext_vector_type(8)));
typedef float f32x4 __attribute__((ext_vector_type(4)));
typedef unsigned int u32x4 __attribute__((ext_vector_type(4)));

// ---------------- constants ----------------
#define BATCH 8
#define SEQ   2048
#define DIM   1024
#define M_TOT (BATCH * SEQ)      // 16384
#define N_QKV (3 * DIM)          // 3072

// workspace layout (bytes) — peak 201,326,592 (192 MiB)
//   [0, 100663296)            qkv bf16 (16384 x 3072)
//   [100663296, 134217728)    vt  bf16 (8 x 1024 x 2048)
//   [134217728, ...)          region C, time-multiplexed:
//       phase 1: xb bf16 (33,554,432) + wt bf16 (6,291,456)   [dead after QKV GEMM]
//       phase 2: S/P bf16 (8 x 2048 x 2048 x 2 = 67,108,864)  [softmax in-place]
#define OFF_QKV  ((size_t)0)
#define OFF_VT   ((size_t)100663296)
#define OFF_C    ((size_t)134217728)
#define OFF_XB   OFF_C
#define OFF_WT   (OFF_C + (size_t)33554432)
#define OFF_S    OFF_C

__device__ __forceinline__ u16 f32_to_bf16(float f) {
    u32 u = __builtin_bit_cast(u32, f);
    u = (u + 0x7fffu + ((u >> 16) & 1u)) >> 16;
    return (u16)u;
}

__device__ __forceinline__ float bf16_to_f32(u16 h) {
    u32 u = ((u32)h) << 16;
    return __builtin_bit_cast(float, u);
}

__device__ __forceinline__ bf16x8 lds_load8(const u16* p) {
    return __builtin_bit_cast(bf16x8, *(const u32x4*)p);
}

// ---- BK=64 tile staging ----
// 128x64 bf16 tile = 16 KB = 1024 16B-chunks; 256 threads x 4 issues.
// Chunk slot s holds data (row = s>>3, kg = (s&7) ^ (row&7)) — XOR swizzle
// spreads each 16-lane row-cluster of the fragment reads across all 8
// bank-quads (8 lanes/quad per b128 = conflict-free optimal; R3 verified
// the BK=32 variant of this swizzle drops SQ_LDS_BANK_CONFLICT to 0).
__device__ __forceinline__ void stage_tile64(const u16* gA, size_t lda, u16* ldsA, int tid) {
    int wv = tid >> 6;
#pragma unroll
    for (int iss = 0; iss < 4; ++iss) {
        int s = iss * 256 + tid;            // chunk slot 0..1023
        int row = s >> 3;                   // 8 chunks per 64-wide row
        int kg = (s & 7) ^ (row & 7);       // swizzled k-group for this slot
        const u16* gp = gA + (size_t)row * lda + (kg << 3);
        u16* lp = ldsA + (size_t)(iss * 256 + wv * 64) * 8;  // wave-uniform base
        __builtin_amdgcn_global_load_lds((const __attribute__((address_space(1))) void*)gp,
                                         (__attribute__((address_space(3))) void*)lp,
                                         16, 0, 0);
    }
}

// Two K=32 sub-steps over a 128x64 LDS tile: 4x4 fragments of 16x16x32 per
// sub-step, per-wave 64x64 of a 128x128 C tile. (wr+i*16)%8==0 so the
// swizzle term depends only on lane — zero extra inner-loop VALU.
__device__ __forceinline__ void mfma_step64(const u16* ldsA, const u16* ldsB, int tid,
                                            f32x4 acc[4][4]) {
    int lane = tid & 63;
    int wv = tid >> 6;
    int wr = (wv >> 1) * 64, wc = (wv & 1) * 64;
    int lrow = lane & 15, kgl = lane >> 4;
    int xr = lrow & 7;
#pragma unroll
    for (int ks = 0; ks < 2; ++ks) {
        int off = ((ks * 4 + kgl) ^ xr) << 3;
        bf16x8 a[4], b[4];
#pragma unroll
        for (int i = 0; i < 4; ++i) {
            a[i] = lds_load8(&ldsA[(wr + i * 16 + lrow) * 64 + off]);
            b[i] = lds_load8(&ldsB[(wc + i * 16 + lrow) * 64 + off]);
        }
#pragma unroll
        for (int i = 0; i < 4; ++i)
#pragma unroll
            for (int j = 0; j < 4; ++j)
                acc[i][j] = __builtin_amdgcn_mfma_f32_16x16x32_bf16(a[i], b[j], acc[i][j], 0, 0, 0);
    }
}

// ---------------- kernel 1: cast x fp32 -> bf16 ----------------
__global__ __launch_bounds__(256) void cast_x_kernel(const float* __restrict__ x,
                                                     u16* __restrict__ xb) {
    size_t g = (size_t)blockIdx.x * 256 + threadIdx.x;   // group of 4 elems
    f32x4 v = ((const f32x4*)x)[g];
    u16 o[4] = {f32_to_bf16(v.x), f32_to_bf16(v.y), f32_to_bf16(v.z), f32_to_bf16(v.w)};
    *(unsigned long long*)(xb + g * 4) = *(const unsigned long long*)o;
}

// ---------------- kernel 2: transpose-cast W [k][n] fp32 -> Wt [n][k] bf16 ----------------
__global__ __launch_bounds__(256) void transpose_w_kernel(const float* __restrict__ wq,
                                                          const float* __restrict__ wk,
                                                          const float* __restrict__ wv,
                                                          u16* __restrict__ wt) {
    __shared__ __align__(16) u16 tile[64][80];
    const float* w = blockIdx.z == 0 ? wq : (blockIdx.z == 1 ? wk : wv);
    int k0 = blockIdx.x * 64, n0 = blockIdx.y * 64;
    for (int g = threadIdx.x; g < 1024; g += 256) {
        int r = g >> 4, c = (g & 15) << 2;
        f32x4 v = *(const f32x4*)(w + (size_t)(k0 + r) * 1024 + n0 + c);
        tile[r][c + 0] = f32_to_bf16(v.x);
        tile[r][c + 1] = f32_to_bf16(v.y);
        tile[r][c + 2] = f32_to_bf16(v.z);
        tile[r][c + 3] = f32_to_bf16(v.w);
    }
    __syncthreads();
    u16* out = wt + (size_t)blockIdx.z * 1024 * 1024;
    for (int g = threadIdx.x; g < 512; g += 256) {
        int nr = g >> 3, kc = (g & 7) << 3;
        __align__(16) u16 tmp[8];
#pragma unroll
        for (int i = 0; i < 8; ++i) tmp[i] = tile[kc + i][nr];
        *(u32x4*)(out + (size_t)(n0 + nr) * 1024 + k0 + kc) = *(const u32x4*)tmp;
    }
}

// ---------------- kernel 3: QKV GEMM: qkv[m][n'] = xb[m][:] . wt[n'][:] ----------------
__global__ __launch_bounds__(256, 2) void gemm_qkv_kernel(const u16* __restrict__ xb,
                                                          const u16* __restrict__ wt,
                                                          u16* __restrict__ qkv) {
    __shared__ __align__(16) u16 ldsA[128 * 64];
    __shared__ __align__(16) u16 ldsB[128 * 64];
    int nt = blockIdx.x, mt = blockIdx.y;
    const u16* A = xb + (size_t)mt * 128 * 1024;
    const u16* B = wt + (size_t)nt * 128 * 1024;
    int tid = threadIdx.x;
    f32x4 acc[4][4] = {};
    for (int kt = 0; kt < 16; ++kt) {
        __syncthreads();
        stage_tile64(A + kt * 64, 1024, ldsA, tid);
        stage_tile64(B + kt * 64, 1024, ldsB, tid);
        __syncthreads();
        mfma_step64(ldsA, ldsB, tid, acc);
    }
    int lane = tid & 63, wv = tid >> 6;
    int wr = (wv >> 1) * 64, wc = (wv & 1) * 64;
    int r0 = (lane >> 4) * 4, c0 = lane & 15;
    size_t mbase = (size_t)mt * 128;
    int nbase = nt * 128;
#pragma unroll
    for (int i = 0; i < 4; ++i)
#pragma unroll
        for (int j = 0; j < 4; ++j) {
            int col = nbase + wc + j * 16 + c0;
            float scale = (col < 1024) ? 0.03125f : 1.0f;  // fold 1/sqrt(1024) into Q
#pragma unroll
            for (int r = 0; r < 4; ++r) {
                int row = wr + i * 16 + r0 + r;
                qkv[(mbase + row) * (size_t)N_QKV + col] = f32_to_bf16(acc[i][j][r] * scale);
            }
        }
}

// ---------------- kernel 4: transpose V -> Vt [b][d][m] ----------------
__global__ __launch_bounds__(256) void transpose_v_kernel(const u16* __restrict__ qkv,
                                                          u16* __restrict__ vt) {
    __shared__ __align__(16) u16 tile[64][80];
    int m0 = blockIdx.x * 64, d0 = blockIdx.y * 64, b = blockIdx.z;
    const u16* src = qkv + (size_t)b * SEQ * N_QKV + 2048;  // V columns
    for (int g = threadIdx.x; g < 512; g += 256) {
        int r = g >> 3, c = (g & 7) << 3;
        *(u32x4*)&tile[r][c] = *(const u32x4*)(src + (size_t)(m0 + r) * N_QKV + d0 + c);
    }
    __syncthreads();
    u16* dst = vt + (size_t)b * DIM * SEQ;
    for (int g = threadIdx.x; g < 512; g += 256) {
        int dr = g >> 3, mc = (g & 7) << 3;
        __align__(16) u16 tmp[8];
#pragma unroll
        for (int i = 0; i < 8; ++i) tmp[i] = tile[mc + i][dr];
        *(u32x4*)(dst + (size_t)(d0 + dr) * SEQ + m0 + mc) = *(const u32x4*)tmp;
    }
}

// ---------------- kernel 5: S = Q . K^T, triangular grid, bf16 output ----------------
__global__ __launch_bounds__(256, 2) void gemm_scores_kernel(const u16* __restrict__ qkv,
                                                             u16* __restrict__ S) {
    int t = blockIdx.x;      // 0..135 triangular index
    int b = blockIdx.y;
    int ntile = (int)((sqrtf(8.0f * (float)t + 1.0f) - 1.0f) * 0.5f);
    while ((ntile + 1) * (ntile + 2) / 2 <= t) ++ntile;
    while (ntile * (ntile + 1) / 2 > t) --ntile;
    int mtile = t - ntile * (ntile + 1) / 2;   // 0 <= mtile <= ntile
    __shared__ __align__(16) u16 ldsA[128 * 64];
    __shared__ __align__(16) u16 ldsB[128 * 64];
    const u16* A = qkv + (size_t)b * SEQ * N_QKV + (size_t)ntile * 128 * N_QKV;        // Q rows
    const u16* B = qkv + (size_t)b * SEQ * N_QKV + (size_t)mtile * 128 * N_QKV + 1024; // K rows
    int tid = threadIdx.x;
    f32x4 acc[4][4] = {};
    for (int kt = 0; kt < 16; ++kt) {
        __syncthreads();
        stage_tile64(A + kt * 64, N_QKV, ldsA, tid);
        stage_tile64(B + kt * 64, N_QKV, ldsB, tid);
        __syncthreads();
        mfma_step64(ldsA, ldsB, tid, acc);
    }
    u16* out = S + (size_t)b * SEQ * SEQ + (size_t)ntile * 128 * SEQ + (size_t)mtile * 128;
    int lane = tid & 63, wv = tid >> 6;
    int wr = (wv >> 1) * 64, wc = (wv & 1) * 64;
    int r0 = (lane >> 4) * 4, c0 = lane & 15;
#pragma unroll
    for (int i = 0; i < 4; ++i)
#pragma unroll
        for (int j = 0; j < 4; ++j) {
            int col = wc + j * 16 + c0;
#pragma unroll
            for (int r = 0; r < 4; ++r) {
                int row = wr + i * 16 + r0 + r;
                out[(size_t)row * SEQ + col] = f32_to_bf16(acc[i][j][r]);
            }
        }
}

// ---------------- kernel 6: row softmax over bf16 S, in-place, register-resident ----
// 256 threads x 8 elems = 2048 = full row. Each thread loads/stores its own
// 16B — perfectly coalesced, one pass, no LDS row buffer.
__global__ __launch_bounds__(256) void softmax_kernel(u16* __restrict__ SP) {
    int gr = blockIdx.x;
    int n = gr & 2047;
    u16* s = SP + (size_t)gr * SEQ;
    __shared__ float red[4];
    int t = threadIdx.x;
    int base = t << 3;
    int len = n + 1;
    float v[8];
    float lmax = -3.0e38f;
    if (base < len) {
        u32x4 raw = *(const u32x4*)(s + base);
        const u16* h = (const u16*)&raw;
#pragma unroll
        for (int i = 0; i < 8; ++i) {
            v[i] = (base + i < len) ? bf16_to_f32(h[i]) : -3.0e38f;
            lmax = fmaxf(lmax, v[i]);
        }
    } else {
#pragma unroll
        for (int i = 0; i < 8; ++i) v[i] = -3.0e38f;
    }
#pragma unroll
    for (int off = 32; off; off >>= 1) lmax = fmaxf(lmax, __shfl_xor(lmax, off, 64));
    if ((t & 63) == 0) red[t >> 6] = lmax;
    __syncthreads();
    float gmax = fmaxf(fmaxf(red[0], red[1]), fmaxf(red[2], red[3]));
    __syncthreads();   // everyone has gmax before red is reused
    float lsum = 0.f;
#pragma unroll
    for (int i = 0; i < 8; ++i) {
        float e = __expf(v[i] - gmax);   // masked lanes -> exp(-huge) = 0
        v[i] = e;
        lsum += e;
    }
#pragma unroll
    for (int off = 32; off; off >>= 1) lsum += __shfl_xor(lsum, off, 64);
    if ((t & 63) == 0) red[t >> 6] = lsum;
    __syncthreads();
    float inv = 1.0f / (red[0] + red[1] + red[2] + red[3]);
    __align__(16) u16 o[8];
#pragma unroll
    for (int i = 0; i < 8; ++i) o[i] = f32_to_bf16(v[i] * inv);  // masked lanes write 0
    *(u32x4*)(s + base) = *(const u32x4*)o;
}

// ---------------- kernel 7: O = P . V (via Vt), causal K truncation ----------------
// ntile reversed so the longest blocks (kTiles=32) dispatch first (tail balance).
__global__ __launch_bounds__(256, 2) void gemm_out_kernel(const u16* __restrict__ P,
                                                          const u16* __restrict__ vt,
                                                          float* __restrict__ O) {
    __shared__ __align__(16) u16 ldsA[128 * 64];
    __shared__ __align__(16) u16 ldsB[128 * 64];
    int dt = blockIdx.x, b = blockIdx.z;
    int ntile = (SEQ / 128 - 1) - blockIdx.y;
    const u16* A = P + (size_t)b * SEQ * SEQ + (size_t)ntile * 128 * SEQ;
    const u16* B = vt + (size_t)b * DIM * SEQ + (size_t)dt * 128 * SEQ;
    int tid = threadIdx.x;
    f32x4 acc[4][4] = {};
    int kTiles = ntile * 2 + 2;  // keys beyond n0+127 have P == 0 (BK=64 units)
    for (int kt = 0; kt < kTiles; ++kt) {
        __syncthreads();
        stage_tile64(A + kt * 64, SEQ, ldsA, tid);
        stage_tile64(B + kt * 64, SEQ, ldsB, tid);
        __syncthreads();
        mfma_step64(ldsA, ldsB, tid, acc);
    }
    float* out = O + (size_t)b * SEQ * DIM + (size_t)ntile * 128 * DIM + (size_t)dt * 128;
    int lane = tid & 63, wv = tid >> 6;
    int wr = (wv >> 1) * 64, wc = (wv & 1) * 64;
    int r0 = (lane >> 4) * 4, c0 = lane & 15;
#pragma unroll
    for (int i = 0; i < 4; ++i)
#pragma unroll
        for (int j = 0; j < 4; ++j) {
            int col = wc + j * 16 + c0;
#pragma unroll
            for (int r = 0; r < 4; ++r) {
                int row = wr + i * 16 + r0 + r;
                out[(size_t)row * DIM + col] = acc[i][j][r];
            }
        }
}

extern "C" void kernel_launch(void* const* d_in, const int* in_sizes, int n_in,
                              void* d_out, int out_size, void* d_ws, size_t ws_size,
                              hipStream_t stream) {
    const float* x = (const float*)d_in[0];
    const float* wq = (const float*)d_in[1];
    const float* wk = (const float*)d_in[2];
    const float* wv = (const float*)d_in[3];
    char* ws = (char*)d_ws;
    u16* qkv = (u16*)(ws + OFF_QKV);
    u16* vt = (u16*)(ws + OFF_VT);
    u16* xb = (u16*)(ws + OFF_XB);
    u16* wt = (u16*)(ws + OFF_WT);
    u16* S = (u16*)(ws + OFF_S);   // aliases xb/wt region (dead by then)
    float* O = (float*)d_out;

    cast_x_kernel<<<M_TOT * DIM / 4 / 256, 256, 0, stream>>>(x, xb);
    transpose_w_kernel<<<dim3(16, 16, 3), 256, 0, stream>>>(wq, wk, wv, wt);
    gemm_qkv_kernel<<<dim3(N_QKV / 128, M_TOT / 128), 256, 0, stream>>>(xb, wt, qkv);
    transpose_v_kernel<<<dim3(SEQ / 64, DIM / 64, BATCH), 256, 0, stream>>>(qkv, vt);
    gemm_scores_kernel<<<dim3(136, BATCH), 256, 0, stream>>>(qkv, S);
    softmax_kernel<<<BATCH * SEQ, 256, 0, stream>>>(S);
    gemm_out_kernel<<<dim3(DIM / 128, SEQ / 128, BATCH), 256, 0, stream>>>(S, vt, O);
}